// Round 5
// baseline (148.889 us; speedup 1.0000x reference)
//
#include <hip/hip_runtime.h>
#include <math.h>

#define TOPK 4
#define WAVE 64
#define WPB 4                    // waves (tiles) per 256-thread block
#define ROUNDS 9                 // 9 DMA rounds x 64 lanes x 16 B = 9216 B / tile
#define STAGE (ROUNDS * 256)     // 2304 floats staged (tile mean 2048 + 5.6 sigma)
#define PAD 8                    // unroll-2 overread pad (reads reach STAGE+6)

// Full-tile wave-private staging, SINGLE buffer. Round-4 evidence: chunked
// staging starves 48/64 lanes (only lanes whose segments intersect the
// chunk work); full-tile staging keeps all lanes scanning concurrently.
// Single-buffering halves LDS vs the double-buffered baseline: 9.25 KB/wave
// -> 4 blocks/CU = 16 waves/CU (4/SIMD), enough TLP to hide the one exposed
// DMA wait (~900 cy) under other waves' scans (~2400 cy). No syncthreads.
__device__ __forceinline__ void dma_tile(const float* __restrict__ scores,
                                         int base, int clamp_hi, float* dst, int lane)
{
#pragma unroll
    for (int r = 0; r < ROUNDS; ++r) {
        int src = base + (r << 8) + (lane << 2);
        src = src < clamp_hi ? src : clamp_hi;   // clamped lanes masked by scan
        __builtin_amdgcn_global_load_lds(
            (const __attribute__((address_space(1))) void*)(scores + src),
            (__attribute__((address_space(3))) void*)(dst + (r << 8)),
            16, 0, 0);
    }
}

__global__ __launch_bounds__(WPB * WAVE) void segment_top4_kernel(
    const int* __restrict__ row_ptr,
    const float* __restrict__ scores,
    float* __restrict__ vals_out,   // [N,4] float32
    float* __restrict__ idx_out,    // [N,4] indices as float32
    int n_nodes, int n_edges, int n_tiles)
{
    __shared__ float lds[WPB][STAGE + PAD];

    int lane = threadIdx.x & (WAVE - 1);
    int wid  = threadIdx.x >> 6;
    int tile = blockIdx.x * WPB + wid;
    if (tile >= n_tiles) return;              // wave-uniform exit

    // Tile base via forced-scalar load (s_load, lgkm counter) so the DMA
    // issues before the vector bounds loads complete.
    int tile_u = __builtin_amdgcn_readfirstlane(tile);
    int base = row_ptr[tile_u << 6] & ~3;     // 16B-aligned float index
    dma_tile(scores, base, n_edges - 4, lds[wid], lane);

    // Per-lane segment bounds (coalesced vector loads, overlap the DMA).
    int node = (tile << 6) + lane;
    int sb = row_ptr[min(node, n_nodes)];
    int se = row_ptr[min(node + 1, n_nodes)];

    // ---- top-4 insert state: f32 value + int index (full-rate VALU).
    // Strict '>' while scanning in increasing edge order == reference
    // tie-break (score desc, index asc). -inf never displaces anything.
    float v0 = -INFINITY, v1 = -INFINITY, v2 = -INFINITY, v3 = -INFINITY;
    int   i0 = -1, i1 = -1, i2 = -1, i3 = -1;
    auto ins = [&](float s, int ei) {
        bool g0 = s > v0, g1 = s > v1, g2 = s > v2, g3 = s > v3;
        v3 = g3 ? (g2 ? v2 : s) : v3;  i3 = g3 ? (g2 ? i2 : ei) : i3;
        v2 = g2 ? (g1 ? v1 : s) : v2;  i2 = g2 ? (g1 ? i1 : ei) : i2;
        v1 = g1 ? (g0 ? v0 : s) : v1;  i1 = g1 ? (g0 ? i0 : ei) : i1;
        v0 = g0 ? s : v0;              i0 = g0 ? ei : i0;
    };

    asm volatile("s_waitcnt vmcnt(0)" ::: "memory");   // tile staged + bounds

    // ---- scan: every lane walks its whole segment; all 64 lanes of the
    // wave are concurrently busy (only mean/max segment-length tail idles).
    const float* buf = lds[wid];
    int lim = min(se, base + STAGE);
    unsigned rng = (unsigned)(se - sb);       // live iff (unsigned)(e-sb) < rng
    int e0 = sb & ~3;                         // 16B-aligned -> ds_read_b128
    for (int e = e0; e < lim; e += 8) {       // unroll-2: 8 edges / iter
        int l = e - base;
        float4 qa = *(const float4*)(buf + l);
        float4 qb = *(const float4*)(buf + l + 4);
        unsigned off = (unsigned)(e - sb);    // wraps below sb -> masked
        ins(off      < rng ? qa.x : -INFINITY, e);
        ins(off + 1u < rng ? qa.y : -INFINITY, e + 1);
        ins(off + 2u < rng ? qa.z : -INFINITY, e + 2);
        ins(off + 3u < rng ? qa.w : -INFINITY, e + 3);
        ins(off + 4u < rng ? qb.x : -INFINITY, e + 4);
        ins(off + 5u < rng ? qb.y : -INFINITY, e + 5);
        ins(off + 6u < rng ? qb.z : -INFINITY, e + 6);
        ins(off + 7u < rng ? qb.w : -INFINITY, e + 7);
    }
    // Overflow fallback: segment runs past the staged window (~never; exact).
    for (int e = max(sb, lim); e < se; ++e)
        ins(scores[e], e);

    // ---- store (coalesced float4 per lane) ----
    if (node < n_nodes) {
        float4 vo, io;
        vo.x = v0; vo.y = v1; vo.z = v2; vo.w = v3;
        io.x = (float)i0; io.y = (float)i1; io.z = (float)i2; io.w = (float)i3;
        *(float4*)(vals_out + (size_t)node * 4) = vo;
        *(float4*)(idx_out + (size_t)node * 4) = io;
    }
}

extern "C" void kernel_launch(void* const* d_in, const int* in_sizes, int n_in,
                              void* d_out, int out_size, void* d_ws, size_t ws_size,
                              hipStream_t stream)
{
    const int*   row_ptr = (const int*)d_in[0];
    const float* scores  = (const float*)d_in[1];
    int n_nodes = in_sizes[0] - 1;
    int n_edges = in_sizes[1];
    int n_tiles = (n_nodes + 63) >> 6;

    float* out      = (float*)d_out;
    float* vals_out = out;                           // first N*4 floats
    float* idx_out  = out + (size_t)n_nodes * TOPK;  // next N*4 floats (idx as f32)

    int grid = (n_tiles + WPB - 1) / WPB;
    segment_top4_kernel<<<grid, WPB * WAVE, 0, stream>>>(
        row_ptr, scores, vals_out, idx_out, n_nodes, n_edges, n_tiles);
}